// Round 6
// baseline (736.175 us; speedup 1.0000x reference)
//
#include <hip/hip_runtime.h>
#include <hip/hip_bf16.h>

// Problem constants
#define NB   128     // frames
#define NP   4096    // points per frame
#define NGRP 16
#define C3   512

typedef __bf16 bf16x8 __attribute__((ext_vector_type(8)));
typedef __bf16 bf16x4 __attribute__((ext_vector_type(4)));
typedef float  f32x4  __attribute__((ext_vector_type(4)));

// ws layout (bytes) — weights in MFMA A-fragment chunk order:
// chunk c holds A[m=l15][k=quad*8+j] as elem c*512 + lane*8 + j
#define WS_W1F_G 0        // 4 chunks (64ch x K32, k>=4 zero)
#define WS_W1F_L 4096
#define WS_W2F_G 8192     // 16 chunks (128ch x K64): c = (ch>>4)*2 + (k>>5)
#define WS_W2F_L 24576
#define WS_W3F_G 40960    // 128 chunks (512ch x K128): c = (ch>>4)*4 + (k>>5)
#define WS_W3F_L 172032
#define WS_GMAX  303104   // [16][512] f32

__global__ __launch_bounds__(256) void prep_kernel(
    const float* __restrict__ Wg1, const float* __restrict__ Wg2, const float* __restrict__ Wg3,
    const float* __restrict__ Wl1, const float* __restrict__ Wl2, const float* __restrict__ Wl3,
    float* __restrict__ out, char* __restrict__ ws) {
    const int t = blockIdx.x, tid = threadIdx.x;
    if (t >= 37) {   // zero z region of out (atomic targets): 64 blocks x 2048 floats
        #pragma unroll
        for (int j = 0; j < 8; ++j) out[(t - 37) * 2048 + j * 256 + tid] = 0.0f;
        return;
    }
    if (t == 36) {   // W1 frags (both branches) + gmax zero
        float* gmax = (float*)(ws + WS_GMAX);
        #pragma unroll
        for (int k = 0; k < 32; ++k) gmax[k * 256 + tid] = 0.0f;
        int c = tid >> 6, lane = tid & 63;
        int ch = c * 16 + (lane & 15);
        int kb = (lane >> 4) * 8;
        bf16x8 pg, pl;
        #pragma unroll
        for (int j = 0; j < 8; ++j) {
            int k = kb + j;
            pg[j] = (k < 4) ? (__bf16)Wg1[k * 64 + ch] : (__bf16)0.0f;
            pl[j] = (k < 4) ? (__bf16)Wl1[k * 64 + ch] : (__bf16)0.0f;
        }
        *(bf16x8*)((__bf16*)(ws + WS_W1F_G) + c * 512 + lane * 8) = pg;
        *(bf16x8*)((__bf16*)(ws + WS_W1F_L) + c * 512 + lane * 8) = pl;
        return;
    }
    // W2/W3 transpose-to-fragment tiles via LDS (coalesced both sides)
    __shared__ float tile[64][65];
    const float* src; __bf16* dst; int cBase, mMul, srcStride;
    if (t < 32) {       // W3 [128k][512ch]: tiles 64x64, (tk 0..1, tc 0..7) per branch
        int branch = t >> 4, rem = t & 15;
        int tk = rem >> 3, tc = rem & 7;
        src = (branch ? Wl3 : Wg3) + (size_t)(tk * 64) * 512 + tc * 64;
        dst = (__bf16*)(ws + (branch ? WS_W3F_L : WS_W3F_G));
        cBase = tc * 16 + tk * 2; mMul = 4; srcStride = 512;
    } else {            // W2 [64k][128ch]: tiles 64x64, tc 0..1 per branch
        int u = t - 32; int branch = u >> 1, tc = u & 1;
        src = (branch ? Wl2 : Wg2) + tc * 64;
        dst = (__bf16*)(ws + (branch ? WS_W2F_L : WS_W2F_G));
        cBase = tc * 8; mMul = 2; srcStride = 128;
    }
    {
        int r0 = tid >> 6, cl = tid & 63;
        #pragma unroll
        for (int p = 0; p < 16; ++p)
            tile[p * 4 + r0][cl] = src[(size_t)(p * 4 + r0) * srcStride + cl];
    }
    __syncthreads();
    int lane = tid & 63, l15 = lane & 15, q = lane >> 4;
    #pragma unroll
    for (int cc = 0; cc < 2; ++cc) {
        int pair = (tid >> 6) * 2 + cc;     // (mi,ks) 0..7
        int mi = pair >> 1, ks = pair & 1;
        bf16x8 pk;
        #pragma unroll
        for (int j = 0; j < 8; ++j) pk[j] = (__bf16)tile[ks * 32 + q * 8 + j][mi * 16 + l15];
        *(bf16x8*)(dst + (cBase + mi * mMul + ks) * 512 + lane * 8) = pk;
    }
}

// Grid (512, 2) = 1024 blocks -> 2 resident blocks/CU (LDS 41.7 KB, VGPR<=128).
// Block = 1024 pts of one frame, 16 macros of 64 pts. Per macro:
//  L1: waves 0-3 only, wave-private 16 pts, 4 MFMA -> h1f chunks.
//  L2: all waves, 16-ch slice (W2 slice reg-resident) x 64 pts, 8 MFMA -> h2f.
//  P2: all waves, 64-ch slice (W3 64 VGPR resident) x 64 pts, 64 MFMA.
// h2f double-buffered; 2 barriers/macro; L1(m+1)/L2(m+1) interleaved into
// P2(m)'s two halves. Co-resident block covers barrier stalls.
// bias3+relu commute with max -> applied once at the end.
__global__ __launch_bounds__(512, 4) void main_kernel(
    const float* __restrict__ pc, const float* __restrict__ tt, const int* __restrict__ idx,
    const float* __restrict__ bg1, const float* __restrict__ bg2, const float* __restrict__ bg3,
    const float* __restrict__ bl1, const float* __restrict__ bl2, const float* __restrict__ bl3,
    float* __restrict__ out, char* __restrict__ ws) {
    __shared__ __align__(16) char smem[41728];
    __bf16* h2f = (__bf16*)smem;               // 2 x 8192 elems (32768 B)
    __bf16* h1f = (__bf16*)(smem + 32768);     // 4096 elems (8192 B); reused as fscr
    float*  b1s = (float*)(smem + 40960);      // 64 f32
    float*  b2s = (float*)(smem + 41216);      // 128 f32

    const int tid = threadIdx.x, lane = tid & 63, wave = tid >> 6;
    const int quad = lane >> 4, l15 = lane & 15;
    const int branch = blockIdx.y;
    const int frame = blockIdx.x >> 2, p0 = (blockIdx.x & 3) * 1024;

    const float* pcx = pc + (size_t)frame * 3 * NP;

    // pc passthrough: branch-0 blocks copy their quarter (overlaps compute)
    if (branch == 0) {
        f32x4* pd = (f32x4*)(out + NB * 2 * C3 + (size_t)frame * 3 * NP + p0);
        const f32x4* ps = (const f32x4*)(pcx + p0);
        for (int i = tid; i < 768; i += 512) {
            int r = i >> 8, col = i & 255;
            pd[r * (NP / 4) + col] = ps[r * (NP / 4) + col];
        }
    }

    const __bf16* w1g = (const __bf16*)(ws + (branch ? WS_W1F_L : WS_W1F_G));
    const __bf16* w2g = (const __bf16*)(ws + (branch ? WS_W2F_L : WS_W2F_G));
    const __bf16* w3g = (const __bf16*)(ws + (branch ? WS_W3F_L : WS_W3F_G));
    const float* b1 = branch ? bl1 : bg1;
    const float* b2 = branch ? bl2 : bg2;
    const float* b3 = branch ? bl3 : bg3;

    if (tid < 64)  b1s[tid] = b1[tid];
    if (tid < 128) b2s[tid] = b2[tid];

    // resident frags: W1 16 VGPR (used by waves 0-3), W2 slice 8, W3 slice 64
    bf16x8 a1[4];
    #pragma unroll
    for (int mi = 0; mi < 4; ++mi) a1[mi] = *(const bf16x8*)(w1g + mi * 512 + lane * 8);
    bf16x8 a2[2];
    #pragma unroll
    for (int ks = 0; ks < 2; ++ks)
        a2[ks] = *(const bf16x8*)(w2g + (wave * 2 + ks) * 512 + lane * 8);
    bf16x8 aw[4][4];
    #pragma unroll
    for (int mi = 0; mi < 4; ++mi)
        #pragma unroll
        for (int ks = 0; ks < 4; ++ks)
            aw[mi][ks] = *(const bf16x8*)(w3g + ((wave * 4 + mi) * 4 + ks) * 512 + lane * 8);

    const float tval = tt[frame];
    const f32x4 zf = {0.0f, 0.0f, 0.0f, 0.0f};
    f32x4 runmax[4];
    #pragma unroll
    for (int mi = 0; mi < 4; ++mi) runmax[mi] = (f32x4){-1e30f, -1e30f, -1e30f, -1e30f};

    const bool l1wave = (wave < 4);
    const int pw = (wave & 3) * 16 + l15;   // L1 point within a macro (waves 0-3)
    const int kq2 = (wave * 2 + (quad >> 1)) & 3;   // h2f write sub-k
    const int s2  = wave >> 1;                       // h2f write k-slice

    // ---- L1: own 16 pts -> h1f chunks (chunk = (pt16)*2 + (ch>>5))
    auto do_l1 = [&](float xx, float xy, float xz) {
        bf16x8 xb;
        #pragma unroll
        for (int j = 0; j < 8; ++j) xb[j] = (__bf16)0.0f;
        if (quad == 0) { xb[0] = (__bf16)xx; xb[1] = (__bf16)xy; xb[2] = (__bf16)xz; xb[3] = (__bf16)tval; }
        #pragma unroll
        for (int mi = 0; mi < 4; ++mi) {
            f32x4 c = __builtin_amdgcn_mfma_f32_16x16x32_bf16(a1[mi], xb, zf, 0, 0, 0);
            f32x4 bv = *(const f32x4*)(b1s + mi * 16 + quad * 4);
            bf16x4 pk;
            #pragma unroll
            for (int r = 0; r < 4; ++r) pk[r] = (__bf16)fmaxf(c[r] + bv[r], 0.0f);
            const int kq = (mi & 1) * 2 + (quad >> 1);
            *(bf16x4*)(h1f + ((wave & 3) * 2 + (mi >> 1)) * 512 + kq * 128 + l15 * 8 + (quad & 1) * 4) = pk;
        }
    };
    // ---- L2: 16-ch slice x 64 pts, K=64, h1f frag reads (contiguous) -> h2f chunks
    auto do_l2 = [&](__bf16* hbn) {
        #pragma unroll
        for (int ni = 0; ni < 4; ++ni) {
            bf16x8 q0 = *(const bf16x8*)(h1f + (ni * 2 + 0) * 512 + lane * 8);
            bf16x8 q1 = *(const bf16x8*)(h1f + (ni * 2 + 1) * 512 + lane * 8);
            f32x4 c = __builtin_amdgcn_mfma_f32_16x16x32_bf16(a2[0], q0, zf, 0, 0, 0);
            c = __builtin_amdgcn_mfma_f32_16x16x32_bf16(a2[1], q1, c, 0, 0, 0);
            f32x4 bv = *(const f32x4*)(b2s + wave * 16 + quad * 4);
            bf16x4 pk;
            #pragma unroll
            for (int r = 0; r < 4; ++r) pk[r] = (__bf16)fmaxf(c[r] + bv[r], 0.0f);
            *(bf16x4*)(hbn + (ni * 4 + s2) * 512 + kq2 * 128 + l15 * 8 + (quad & 1) * 4) = pk;
        }
    };
    // ---- P2: two 16-pt groups (nibase, +1), 32 MFMA, conflict-free reads
    auto p2_pair = [&](const __bf16* hb, int nibase) {
        bf16x8 bhA[4], bhB[4];
        #pragma unroll
        for (int ks = 0; ks < 4; ++ks)
            bhA[ks] = *(const bf16x8*)(hb + (nibase * 4 + ks) * 512 + lane * 8);
        #pragma unroll
        for (int ks = 0; ks < 4; ++ks)
            bhB[ks] = *(const bf16x8*)(hb + ((nibase + 1) * 4 + ks) * 512 + lane * 8);
        #pragma unroll
        for (int u = 0; u < 2; ++u) {
            const bf16x8* cur = u ? bhB : bhA;
            f32x4 acc[4];
            #pragma unroll
            for (int ks = 0; ks < 4; ++ks)
                #pragma unroll
                for (int mi = 0; mi < 4; ++mi)
                    acc[mi] = __builtin_amdgcn_mfma_f32_16x16x32_bf16(
                        aw[mi][ks], cur[ks], ks ? acc[mi] : zf, 0, 0, 0);
            #pragma unroll
            for (int mi = 0; mi < 4; ++mi)
                #pragma unroll
                for (int r = 0; r < 4; ++r)
                    runmax[mi][r] = fmaxf(runmax[mi][r], acc[mi][r]);
        }
    };

    __syncthreads();   // b1s/b2s ready

    // prologue: macro 0 through L1+L2 into h2f buf 0
    if (l1wave) {
        float xx = pcx[p0 + pw], xy = pcx[NP + p0 + pw], xz = pcx[2 * NP + p0 + pw];
        do_l1(xx, xy, xz);
    }
    __syncthreads();
    do_l2(h2f);

    for (int m = 0; m < 16; ++m) {
        __syncthreads();                       // buf[m&1] ready; h1f consumed
        const __bf16* hb = h2f + (m & 1) * 8192;
        __bf16* hbn = h2f + ((m + 1) & 1) * 8192;
        const bool more = (m < 15);
        float nx = 0.f, ny = 0.f, nz = 0.f;
        if (more && l1wave) {
            const int p = p0 + (m + 1) * 64 + pw;
            nx = pcx[p]; ny = pcx[NP + p]; nz = pcx[2 * NP + p];
        }
        p2_pair(hb, 0);                        // ni 0,1
        if (more && l1wave) do_l1(nx, ny, nz);
        __syncthreads();                       // h1f ready
        p2_pair(hb, 2);                        // ni 2,3
        if (more) do_l2(hbn);                  // write other buffer
    }

    // ---- finalize: fold 16 pt-columns, bias3+relu, one atomic per channel
    const int g = idx[frame];
    float* gmax = (float*)(ws + WS_GMAX);
    unsigned* dst = (branch == 0) ? (unsigned*)(gmax + g * C3)
                                  : (unsigned*)(out + (size_t)frame * (2 * C3) + C3);
    #pragma unroll
    for (int mi = 0; mi < 4; ++mi) {
        f32x4 v = runmax[mi];
        #pragma unroll
        for (int d = 1; d < 16; d <<= 1) {
            #pragma unroll
            for (int r = 0; r < 4; ++r) v[r] = fmaxf(v[r], __shfl_xor(v[r], d));
        }
        if (l15 == 0) {
            #pragma unroll
            for (int r = 0; r < 4; ++r) {
                const int ch = wave * 64 + mi * 16 + quad * 4 + r;
                const float fv = fmaxf(v[r] + b3[ch], 0.0f);
                atomicMax(dst + ch, __float_as_uint(fv));  // relu>=0: uint order == float order
            }
        }
    }
}

__global__ void gather_kernel(const int* __restrict__ idx, const char* __restrict__ ws,
                              float* __restrict__ out) {
    int i = blockIdx.x * blockDim.x + threadIdx.x;   // 0..65535
    int b = i >> 9, ch = i & 511;
    const float* gmax = (const float*)(ws + WS_GMAX);
    out[b * (2 * C3) + ch] = gmax[idx[b] * C3 + ch];
}

extern "C" void kernel_launch(void* const* d_in, const int* in_sizes, int n_in,
                              void* d_out, int out_size, void* d_ws, size_t ws_size,
                              hipStream_t stream) {
    const float* pc  = (const float*)d_in[0];
    const float* tt  = (const float*)d_in[1];
    const int*   idx = (const int*)d_in[2];
    const float* Wg1 = (const float*)d_in[3];  const float* bg1 = (const float*)d_in[4];
    const float* Wg2 = (const float*)d_in[5];  const float* bg2 = (const float*)d_in[6];
    const float* Wg3 = (const float*)d_in[7];  const float* bg3 = (const float*)d_in[8];
    const float* Wl1 = (const float*)d_in[9];  const float* bl1 = (const float*)d_in[10];
    const float* Wl2 = (const float*)d_in[11]; const float* bl2 = (const float*)d_in[12];
    const float* Wl3 = (const float*)d_in[13]; const float* bl3 = (const float*)d_in[14];
    float* out = (float*)d_out;
    char*  ws  = (char*)d_ws;

    // prep: weight frag layout (LDS transpose), gmax zero, z-region zero
    prep_kernel<<<101, 256, 0, stream>>>(Wg1, Wg2, Wg3, Wl1, Wl2, Wl3, out, ws);
    // main: 512 chunks x 2 branches = 1024 blocks, 2 resident/CU
    main_kernel<<<dim3(512, 2), 512, 0, stream>>>(pc, tt, idx, bg1, bg2, bg3,
                                                  bl1, bl2, bl3, out, ws);
    gather_kernel<<<256, 256, 0, stream>>>(idx, ws, out);
}

// Round 7
// 221.714 us; speedup vs baseline: 3.3204x; 3.3204x over previous
//
#include <hip/hip_runtime.h>
#include <hip/hip_bf16.h>

// Problem constants
#define NB   128     // frames
#define NP   4096    // points per frame
#define NGRP 16
#define C3   512

typedef __bf16 bf16x8 __attribute__((ext_vector_type(8)));
typedef __bf16 bf16x4 __attribute__((ext_vector_type(4)));
typedef float  f32x4  __attribute__((ext_vector_type(4)));

// ws layout (bytes) — weights in MFMA A-fragment chunk order:
// chunk c holds A[m=l15][k=quad*8+j] as elem c*512 + lane*8 + j
#define WS_W1F_G 0        // 4 chunks (64ch x K32, k>=4 zero)
#define WS_W1F_L 4096
#define WS_W2F_G 8192     // 16 chunks (128ch x K64): c = (ch>>4)*2 + (k>>5)
#define WS_W2F_L 24576
#define WS_W3F_G 40960    // 128 chunks (512ch x K128): c = (ch>>4)*4 + (k>>5)
#define WS_W3F_L 172032
#define WS_GMAX  303104   // [16][512] f32

__global__ __launch_bounds__(256) void prep_kernel(
    const float* __restrict__ Wg1, const float* __restrict__ Wg2, const float* __restrict__ Wg3,
    const float* __restrict__ Wl1, const float* __restrict__ Wl2, const float* __restrict__ Wl3,
    float* __restrict__ out, char* __restrict__ ws) {
    const int t = blockIdx.x, tid = threadIdx.x;
    if (t >= 37) {   // zero z region of out (atomic targets): 64 blocks x 2048 floats
        #pragma unroll
        for (int j = 0; j < 8; ++j) out[(t - 37) * 2048 + j * 256 + tid] = 0.0f;
        return;
    }
    if (t == 36) {   // W1 frags (both branches) + gmax zero
        float* gmax = (float*)(ws + WS_GMAX);
        #pragma unroll
        for (int k = 0; k < 32; ++k) gmax[k * 256 + tid] = 0.0f;
        int c = tid >> 6, lane = tid & 63;
        int ch = c * 16 + (lane & 15);
        int kb = (lane >> 4) * 8;
        bf16x8 pg, pl;
        #pragma unroll
        for (int j = 0; j < 8; ++j) {
            int k = kb + j;
            pg[j] = (k < 4) ? (__bf16)Wg1[k * 64 + ch] : (__bf16)0.0f;
            pl[j] = (k < 4) ? (__bf16)Wl1[k * 64 + ch] : (__bf16)0.0f;
        }
        *(bf16x8*)((__bf16*)(ws + WS_W1F_G) + c * 512 + lane * 8) = pg;
        *(bf16x8*)((__bf16*)(ws + WS_W1F_L) + c * 512 + lane * 8) = pl;
        return;
    }
    // W2/W3 transpose-to-fragment tiles via LDS (coalesced both sides)
    __shared__ float tile[64][65];
    const float* src; __bf16* dst; int cBase, mMul, srcStride;
    if (t < 32) {       // W3 [128k][512ch]: tiles 64x64, (tk 0..1, tc 0..7) per branch
        int branch = t >> 4, rem = t & 15;
        int tk = rem >> 3, tc = rem & 7;
        src = (branch ? Wl3 : Wg3) + (size_t)(tk * 64) * 512 + tc * 64;
        dst = (__bf16*)(ws + (branch ? WS_W3F_L : WS_W3F_G));
        cBase = tc * 16 + tk * 2; mMul = 4; srcStride = 512;
    } else {            // W2 [64k][128ch]: tiles 64x64, tc 0..1 per branch
        int u = t - 32; int branch = u >> 1, tc = u & 1;
        src = (branch ? Wl2 : Wg2) + tc * 64;
        dst = (__bf16*)(ws + (branch ? WS_W2F_L : WS_W2F_G));
        cBase = tc * 8; mMul = 2; srcStride = 128;
    }
    {
        int r0 = tid >> 6, cl = tid & 63;
        #pragma unroll
        for (int p = 0; p < 16; ++p)
            tile[p * 4 + r0][cl] = src[(size_t)(p * 4 + r0) * srcStride + cl];
    }
    __syncthreads();
    int lane = tid & 63, l15 = lane & 15, q = lane >> 4;
    #pragma unroll
    for (int cc = 0; cc < 2; ++cc) {
        int pair = (tid >> 6) * 2 + cc;     // (mi,ks) 0..7
        int mi = pair >> 1, ks = pair & 1;
        bf16x8 pk;
        #pragma unroll
        for (int j = 0; j < 8; ++j) pk[j] = (__bf16)tile[ks * 32 + q * 8 + j][mi * 16 + l15];
        *(bf16x8*)(dst + (cBase + mi * mMul + ks) * 512 + lane * 8) = pk;
    }
}

// Grid (512, 2) = 1024 blocks, launch_bounds(512,2): VGPR cap 128 and LDS
// 62 KB allow 2 RESIDENT BLOCKS/CU (grid provides 4 waves/SIMD total).
// Block = 1024 pts of one frame, 16 macros of 64 pts. Per macro:
//  L1: waves 0-3 only, wave-private 16 pts, 4 MFMA (W1 frags from LDS) -> h1f.
//  L2: all waves, 16-ch slice x 64 pts (W2 frags from LDS), 8 MFMA -> h2f.
//  P2: all waves, 64-ch slice (W3 = 64 VGPR register-resident) x 64 pts, 64 MFMA.
// h2f double-buffered; 2 barriers/macro; L1(m+1)/L2(m+1) interleaved into
// P2(m). Registers: aw 64 + runmax 16 + bh 16 + acc 16 + addr (~115 < 128).
// bias3+relu commute with max -> applied once at the end.
__global__ __launch_bounds__(512, 2) void main_kernel(
    const float* __restrict__ pc, const float* __restrict__ tt, const int* __restrict__ idx,
    const float* __restrict__ bg1, const float* __restrict__ bg2, const float* __restrict__ bg3,
    const float* __restrict__ bl1, const float* __restrict__ bl2, const float* __restrict__ bl3,
    float* __restrict__ out, char* __restrict__ ws) {
    __shared__ __align__(16) char smem[62208];
    __bf16* h2f = (__bf16*)smem;               // 2 x 8192 elems (32768 B)
    __bf16* h1f = (__bf16*)(smem + 32768);     // 4096 elems (8192 B)
    __bf16* w1s = (__bf16*)(smem + 40960);     // 2048 elems (4096 B)
    __bf16* w2s = (__bf16*)(smem + 45056);     // 8192 elems (16384 B)
    float*  b1s = (float*)(smem + 61440);      // 64 f32
    float*  b2s = (float*)(smem + 61696);      // 128 f32

    const int tid = threadIdx.x, lane = tid & 63, wave = tid >> 6;
    const int quad = lane >> 4, l15 = lane & 15;
    const int branch = blockIdx.y;
    const int frame = blockIdx.x >> 2, p0 = (blockIdx.x & 3) * 1024;

    const float* pcx = pc + (size_t)frame * 3 * NP;

    // pc passthrough: branch-0 blocks copy their quarter (overlaps compute)
    if (branch == 0) {
        f32x4* pd = (f32x4*)(out + NB * 2 * C3 + (size_t)frame * 3 * NP + p0);
        const f32x4* ps = (const f32x4*)(pcx + p0);
        for (int i = tid; i < 768; i += 512) {
            int r = i >> 8, col = i & 255;
            pd[r * (NP / 4) + col] = ps[r * (NP / 4) + col];
        }
    }

    const __bf16* w1g = (const __bf16*)(ws + (branch ? WS_W1F_L : WS_W1F_G));
    const __bf16* w2g = (const __bf16*)(ws + (branch ? WS_W2F_L : WS_W2F_G));
    const __bf16* w3g = (const __bf16*)(ws + (branch ? WS_W3F_L : WS_W3F_G));
    const float* b1 = branch ? bl1 : bg1;
    const float* b2 = branch ? bl2 : bg2;
    const float* b3 = branch ? bl3 : bg3;

    // stage W1+W2 frags and biases into LDS (frees VGPRs for aw)
    for (int i = tid; i < 1280; i += 512) {
        if (i < 256) ((f32x4*)w1s)[i] = ((const f32x4*)w1g)[i];
        else         ((f32x4*)w2s)[i - 256] = ((const f32x4*)w2g)[i - 256];
    }
    if (tid < 64)  b1s[tid] = b1[tid];
    if (tid < 128) b2s[tid] = b2[tid];

    // W3 slice register-resident: 64 ch x K=128 = 64 VGPRs
    bf16x8 aw[4][4];
    #pragma unroll
    for (int mi = 0; mi < 4; ++mi)
        #pragma unroll
        for (int ks = 0; ks < 4; ++ks)
            aw[mi][ks] = *(const bf16x8*)(w3g + ((wave * 4 + mi) * 4 + ks) * 512 + lane * 8);

    const float tval = tt[frame];
    const f32x4 zf = {0.0f, 0.0f, 0.0f, 0.0f};
    f32x4 runmax[4];
    #pragma unroll
    for (int mi = 0; mi < 4; ++mi) runmax[mi] = (f32x4){-1e30f, -1e30f, -1e30f, -1e30f};

    const bool l1wave = (wave < 4);
    const int pw = (wave & 3) * 16 + l15;           // L1 point within a macro
    const int kq2 = (wave * 2 + (quad >> 1)) & 3;   // h2f write sub-k
    const int s2  = wave >> 1;                      // h2f write k-slice

    // ---- L1: own 16 pts -> h1f chunks (chunk = pt16*2 + (ch>>5)); W1 from LDS
    auto do_l1 = [&](float xx, float xy, float xz) {
        bf16x8 xb;
        #pragma unroll
        for (int j = 0; j < 8; ++j) xb[j] = (__bf16)0.0f;
        if (quad == 0) { xb[0] = (__bf16)xx; xb[1] = (__bf16)xy; xb[2] = (__bf16)xz; xb[3] = (__bf16)tval; }
        #pragma unroll
        for (int mi = 0; mi < 4; ++mi) {
            bf16x8 a1 = *(const bf16x8*)(w1s + mi * 512 + lane * 8);
            f32x4 c = __builtin_amdgcn_mfma_f32_16x16x32_bf16(a1, xb, zf, 0, 0, 0);
            f32x4 bv = *(const f32x4*)(b1s + mi * 16 + quad * 4);
            bf16x4 pk;
            #pragma unroll
            for (int r = 0; r < 4; ++r) pk[r] = (__bf16)fmaxf(c[r] + bv[r], 0.0f);
            const int kq = (mi & 1) * 2 + (quad >> 1);
            *(bf16x4*)(h1f + ((wave & 3) * 2 + (mi >> 1)) * 512 + kq * 128 + l15 * 8 + (quad & 1) * 4) = pk;
        }
    };
    // ---- L2: 16-ch slice x 64 pts, K=64; W2 frags from LDS -> h2f chunks
    auto do_l2 = [&](__bf16* hbn) {
        bf16x8 a20 = *(const bf16x8*)(w2s + (wave * 2 + 0) * 512 + lane * 8);
        bf16x8 a21 = *(const bf16x8*)(w2s + (wave * 2 + 1) * 512 + lane * 8);
        #pragma unroll
        for (int ni = 0; ni < 4; ++ni) {
            bf16x8 q0 = *(const bf16x8*)(h1f + (ni * 2 + 0) * 512 + lane * 8);
            bf16x8 q1 = *(const bf16x8*)(h1f + (ni * 2 + 1) * 512 + lane * 8);
            f32x4 c = __builtin_amdgcn_mfma_f32_16x16x32_bf16(a20, q0, zf, 0, 0, 0);
            c = __builtin_amdgcn_mfma_f32_16x16x32_bf16(a21, q1, c, 0, 0, 0);
            f32x4 bv = *(const f32x4*)(b2s + wave * 16 + quad * 4);
            bf16x4 pk;
            #pragma unroll
            for (int r = 0; r < 4; ++r) pk[r] = (__bf16)fmaxf(c[r] + bv[r], 0.0f);
            *(bf16x4*)(hbn + (ni * 4 + s2) * 512 + kq2 * 128 + l15 * 8 + (quad & 1) * 4) = pk;
        }
    };
    // ---- P2: one 16-pt group, 16 MFMA, conflict-free lane-contiguous reads
    auto p2_group = [&](const __bf16* hb, int ni) {
        bf16x8 bh[4];
        #pragma unroll
        for (int ks = 0; ks < 4; ++ks)
            bh[ks] = *(const bf16x8*)(hb + (ni * 4 + ks) * 512 + lane * 8);
        f32x4 acc[4];
        #pragma unroll
        for (int ks = 0; ks < 4; ++ks)
            #pragma unroll
            for (int mi = 0; mi < 4; ++mi)
                acc[mi] = __builtin_amdgcn_mfma_f32_16x16x32_bf16(
                    aw[mi][ks], bh[ks], ks ? acc[mi] : zf, 0, 0, 0);
        #pragma unroll
        for (int mi = 0; mi < 4; ++mi)
            #pragma unroll
            for (int r = 0; r < 4; ++r)
                runmax[mi][r] = fmaxf(runmax[mi][r], acc[mi][r]);
    };

    __syncthreads();   // w1s/w2s/b1s/b2s ready

    // prologue: macro 0 through L1+L2 into h2f buf 0
    if (l1wave) {
        float xx = pcx[p0 + pw], xy = pcx[NP + p0 + pw], xz = pcx[2 * NP + p0 + pw];
        do_l1(xx, xy, xz);
    }
    __syncthreads();
    do_l2(h2f);

    for (int m = 0; m < 16; ++m) {
        __syncthreads();                       // buf[m&1] ready; h1f consumed
        const __bf16* hb = h2f + (m & 1) * 8192;
        __bf16* hbn = h2f + ((m + 1) & 1) * 8192;
        const bool more = (m < 15);
        float nx = 0.f, ny = 0.f, nz = 0.f;
        if (more && l1wave) {
            const int p = p0 + (m + 1) * 64 + pw;
            nx = pcx[p]; ny = pcx[NP + p]; nz = pcx[2 * NP + p];
        }
        p2_group(hb, 0);
        p2_group(hb, 1);
        if (more && l1wave) do_l1(nx, ny, nz);
        __syncthreads();                       // h1f ready
        p2_group(hb, 2);
        p2_group(hb, 3);
        if (more) do_l2(hbn);                  // write other buffer
    }

    // ---- finalize: fold 16 pt-columns, bias3+relu, one atomic per channel
    const int g = idx[frame];
    float* gmax = (float*)(ws + WS_GMAX);
    unsigned* dst = (branch == 0) ? (unsigned*)(gmax + g * C3)
                                  : (unsigned*)(out + (size_t)frame * (2 * C3) + C3);
    #pragma unroll
    for (int mi = 0; mi < 4; ++mi) {
        f32x4 v = runmax[mi];
        #pragma unroll
        for (int d = 1; d < 16; d <<= 1) {
            #pragma unroll
            for (int r = 0; r < 4; ++r) v[r] = fmaxf(v[r], __shfl_xor(v[r], d));
        }
        if (l15 == 0) {
            #pragma unroll
            for (int r = 0; r < 4; ++r) {
                const int ch = wave * 64 + mi * 16 + quad * 4 + r;
                const float fv = fmaxf(v[r] + b3[ch], 0.0f);
                atomicMax(dst + ch, __float_as_uint(fv));  // relu>=0: uint order == float order
            }
        }
    }
}

__global__ void gather_kernel(const int* __restrict__ idx, const char* __restrict__ ws,
                              float* __restrict__ out) {
    int i = blockIdx.x * blockDim.x + threadIdx.x;   // 0..65535
    int b = i >> 9, ch = i & 511;
    const float* gmax = (const float*)(ws + WS_GMAX);
    out[b * (2 * C3) + ch] = gmax[idx[b] * C3 + ch];
}

extern "C" void kernel_launch(void* const* d_in, const int* in_sizes, int n_in,
                              void* d_out, int out_size, void* d_ws, size_t ws_size,
                              hipStream_t stream) {
    const float* pc  = (const float*)d_in[0];
    const float* tt  = (const float*)d_in[1];
    const int*   idx = (const int*)d_in[2];
    const float* Wg1 = (const float*)d_in[3];  const float* bg1 = (const float*)d_in[4];
    const float* Wg2 = (const float*)d_in[5];  const float* bg2 = (const float*)d_in[6];
    const float* Wg3 = (const float*)d_in[7];  const float* bg3 = (const float*)d_in[8];
    const float* Wl1 = (const float*)d_in[9];  const float* bl1 = (const float*)d_in[10];
    const float* Wl2 = (const float*)d_in[11]; const float* bl2 = (const float*)d_in[12];
    const float* Wl3 = (const float*)d_in[13]; const float* bl3 = (const float*)d_in[14];
    float* out = (float*)d_out;
    char*  ws  = (char*)d_ws;

    // prep: weight frag layout (LDS transpose), gmax zero, z-region zero
    prep_kernel<<<101, 256, 0, stream>>>(Wg1, Wg2, Wg3, Wl1, Wl2, Wl3, out, ws);
    // main: 512 chunks x 2 branches = 1024 blocks, 2 resident blocks/CU
    main_kernel<<<dim3(512, 2), 512, 0, stream>>>(pc, tt, idx, bg1, bg2, bg3,
                                                  bl1, bl2, bl3, out, ws);
    gather_kernel<<<256, 256, 0, stream>>>(idx, ws, out);
}